// Round 1
// baseline (675.974 us; speedup 1.0000x reference)
//
#include <hip/hip_runtime.h>
#include <hip/hip_bf16.h>
#include <stdint.h>
#include <stddef.h>

// Problem constants
#define B_   2
#define L_   2048
#define E_   2048
#define H_   16
#define D_   128
#define F_   2048          // QKV_FEATURES
#define NROW (B_*L_)       // 4096

typedef __bf16 bf16_t;
typedef __bf16 bf16x4 __attribute__((ext_vector_type(4)));
typedef __bf16 bf16x8 __attribute__((ext_vector_type(8)));
typedef float  f32x4  __attribute__((ext_vector_type(4)));

// ---------------- fp32 -> bf16 elementwise ----------------
__global__ __launch_bounds__(256) void k_convert(const float* __restrict__ in,
                                                 bf16_t* __restrict__ out, int n4) {
  int i = blockIdx.x*256 + threadIdx.x;
  if (i >= n4) return;
  float4 v = ((const float4*)in)[i];
  bf16x4 t;
  t[0] = (__bf16)v.x; t[1] = (__bf16)v.y; t[2] = (__bf16)v.z; t[3] = (__bf16)v.w;
  ((bf16x4*)out)[i] = t;
}

// ------- transpose+convert: W[2048][2048] f32 -> WT[2048][2048] bf16 -------
__global__ __launch_bounds__(256) void k_transpose_w(const float* __restrict__ in,
                                                     bf16_t* __restrict__ out) {
  __shared__ float tile[32][33];
  const int ct = blockIdx.x, rt = blockIdx.y;
  const int c = threadIdx.x & 31, r0 = threadIdx.x >> 5;
  #pragma unroll
  for (int k = 0; k < 4; k++) {
    int r = r0 + k*8;
    tile[r][c] = in[(size_t)(rt*32 + r)*2048 + ct*32 + c];
  }
  __syncthreads();
  #pragma unroll
  for (int k = 0; k < 4; k++) {
    int r = r0 + k*8;
    out[(size_t)(ct*32 + r)*2048 + rt*32 + c] = (__bf16)tile[c][r];
  }
}

// ---------------- RoPE cos/sin table: [L][64] of float2(cos,sin) ----------------
__global__ __launch_bounds__(256) void k_sincos(float2* __restrict__ sc) {
  int id = blockIdx.x*256 + threadIdx.x;   // L_*64 threads
  int t = id >> 6, i = id & 63;
  float freq = powf(10000.0f, -(float)i / 64.0f);   // theta^(-2i/D)
  float a = (float)t * freq;
  sc[id] = make_float2(cosf(a), sinf(a));
}

// ---------------- in-place RoPE on bf16 [NROW][F_] ----------------
__global__ __launch_bounds__(256) void k_rope(bf16_t* __restrict__ qk,
                                              const float2* __restrict__ sc, int n4) {
  int i = blockIdx.x*256 + threadIdx.x;    // NROW*F_/4 groups (2 pairs each)
  if (i >= n4) return;
  int e  = i << 2;
  int d  = e & (F_-1);
  int ii = (d & (D_-1)) >> 1;              // pair index within head (even)
  int t  = (e >> 11) & (L_-1);             // token position
  bf16x4 v = ((const bf16x4*)qk)[i];
  float2 cs0 = sc[t*64 + ii];
  float2 cs1 = sc[t*64 + ii + 1];
  float x0 = (float)v[0], x1 = (float)v[1], x2 = (float)v[2], x3 = (float)v[3];
  bf16x4 o;
  o[0] = (__bf16)(x0*cs0.x - x1*cs0.y);
  o[1] = (__bf16)(x0*cs0.y + x1*cs0.x);
  o[2] = (__bf16)(x2*cs1.x - x3*cs1.y);
  o[3] = (__bf16)(x2*cs1.y + x3*cs1.x);
  ((bf16x4*)qk)[i] = o;
}

// -------- transpose V: [B][L][H][D] bf16 -> Vt [B][H][D][L] bf16 --------
__global__ __launch_bounds__(256) void k_transpose_v(const bf16_t* __restrict__ in,
                                                     bf16_t* __restrict__ out) {
  __shared__ bf16_t tile[32][33];
  const int lt = blockIdx.x, dt = blockIdx.y, bh = blockIdx.z;
  const int b = bh >> 4;                   // H_=16
  const int h = bh & 15;
  const int c = threadIdx.x & 31, r0 = threadIdx.x >> 5;
  #pragma unroll
  for (int k = 0; k < 4; k++) {
    int r = r0 + k*8;
    tile[r][c] = in[(size_t)(b*L_ + lt*32 + r)*F_ + h*D_ + dt*32 + c];
  }
  __syncthreads();
  #pragma unroll
  for (int k = 0; k < 4; k++) {
    int r = r0 + k*8;
    out[(size_t)(bh*D_ + dt*32 + r)*L_ + lt*32 + c] = tile[c][r];
  }
}

// -------- GEMM: C[M][N] = A[M][K] (bf16) x BT[N][K] (bf16), fp32 accum --------
// 128x128 tile, BK=32, 256 threads (4 waves as 2x2 of 64x64), 16x16x32 MFMA.
template<typename OutT, bool BIAS>
__global__ __launch_bounds__(256) void k_gemm_bt(const bf16_t* __restrict__ A,
                                                 const bf16_t* __restrict__ BT,
                                                 OutT* __restrict__ C,
                                                 const float* __restrict__ bias,
                                                 int M, int N, int K) {
  __shared__ bf16_t As[128*32];
  __shared__ bf16_t Bs[128*32];
  const int tid  = threadIdx.x;
  const int lane = tid & 63, wave = tid >> 6;
  const int wr = wave >> 1, wc = wave & 1;
  const int row0 = blockIdx.y*128, col0 = blockIdx.x*128;
  const int sr  = tid >> 2;                // staging row 0..63
  const int sc8 = (tid & 3) * 8;           // staging col 0/8/16/24
  const bf16_t* Ag = A  + (size_t)(row0 + sr)*K + sc8;
  const bf16_t* Bg = BT + (size_t)(col0 + sr)*K + sc8;
  const int lr = lane & 15, lk = (lane >> 4) * 8;
  f32x4 acc[4][4] = {};
  for (int kt = 0; kt < K; kt += 32) {
    bf16x8 a0 = *(const bf16x8*)(Ag + kt);
    bf16x8 a1 = *(const bf16x8*)(Ag + (size_t)64*K + kt);
    bf16x8 b0 = *(const bf16x8*)(Bg + kt);
    bf16x8 b1 = *(const bf16x8*)(Bg + (size_t)64*K + kt);
    *(bf16x8*)&As[sr*32 + sc8]      = a0;
    *(bf16x8*)&As[(sr+64)*32 + sc8] = a1;
    *(bf16x8*)&Bs[sr*32 + sc8]      = b0;
    *(bf16x8*)&Bs[(sr+64)*32 + sc8] = b1;
    __syncthreads();
    bf16x8 af[4], bb[4];
    #pragma unroll
    for (int m = 0; m < 4; m++) af[m] = *(const bf16x8*)&As[(wr*64 + m*16 + lr)*32 + lk];
    #pragma unroll
    for (int n = 0; n < 4; n++) bb[n] = *(const bf16x8*)&Bs[(wc*64 + n*16 + lr)*32 + lk];
    #pragma unroll
    for (int m = 0; m < 4; m++)
      #pragma unroll
      for (int n = 0; n < 4; n++)
        acc[m][n] = __builtin_amdgcn_mfma_f32_16x16x32_bf16(af[m], bb[n], acc[m][n], 0, 0, 0);
    __syncthreads();
  }
  // epilogue: C/D layout col=lane&15, row=(lane>>4)*4+j (m89-verified)
  #pragma unroll
  for (int m = 0; m < 4; m++) {
    #pragma unroll
    for (int n = 0; n < 4; n++) {
      const int col = col0 + wc*64 + n*16 + lr;
      const float bv = BIAS ? bias[col] : 0.0f;
      #pragma unroll
      for (int j = 0; j < 4; j++) {
        const int row = row0 + wr*64 + m*16 + (lane >> 4)*4 + j;
        C[(size_t)row*N + col] = (OutT)(acc[m][n][j] + bv);
      }
    }
  }
}

// -------- Flash attention, causal. Q,K: [B][L][H*D] bf16 (RoPE'd); Vt: [B][H][D][L] --------
// 4 waves/block, wave owns 32 q-rows; KV tiles of 64; P via swizzled per-wave LDS.
__global__ __launch_bounds__(256) void k_attn(const bf16_t* __restrict__ Q,
                                              const bf16_t* __restrict__ K,
                                              const bf16_t* __restrict__ Vt,
                                              bf16_t* __restrict__ O) {
  __shared__ bf16_t Pl[4][32*64];
  const int lane = threadIdx.x & 63, wave = threadIdx.x >> 6;
  const int qt = blockIdx.x, h = blockIdx.y, b = blockIdx.z;
  const int q0 = qt*128 + wave*32;
  const int lr = lane & 15, lg = lane >> 4, lk = lg*8;
  char* Pb = (char*)&Pl[wave][0];

  bf16x8 aq[2][4];
  #pragma unroll
  for (int m = 0; m < 2; m++)
    #pragma unroll
    for (int kd = 0; kd < 4; kd++)
      aq[m][kd] = *(const bf16x8*)&Q[(size_t)(b*L_ + q0 + m*16 + lr)*F_ + h*D_ + kd*32 + lk];

  f32x4 o[2][8] = {};
  float mrow[2][4], lsum[2][4];
  #pragma unroll
  for (int m = 0; m < 2; m++)
    #pragma unroll
    for (int j = 0; j < 4; j++) { mrow[m][j] = -3.0e38f; lsum[m][j] = 0.0f; }

  const int nt = (q0 + 31)/64 + 1;
  const float scale = 0.08838834764831845f;   // 1/sqrt(128)

  for (int t = 0; t < nt; t++) {
    const int kv0 = t*64;
    f32x4 s[2][4] = {};
    #pragma unroll
    for (int kd = 0; kd < 4; kd++) {
      bf16x8 bk[4];
      #pragma unroll
      for (int n = 0; n < 4; n++)
        bk[n] = *(const bf16x8*)&K[(size_t)(b*L_ + kv0 + n*16 + lr)*F_ + h*D_ + kd*32 + lk];
      #pragma unroll
      for (int m = 0; m < 2; m++)
        #pragma unroll
        for (int n = 0; n < 4; n++)
          s[m][n] = __builtin_amdgcn_mfma_f32_16x16x32_bf16(aq[m][kd], bk[n], s[m][n], 0, 0, 0);
    }
    // scale + causal mask
    #pragma unroll
    for (int m = 0; m < 2; m++)
      #pragma unroll
      for (int n = 0; n < 4; n++)
        #pragma unroll
        for (int j = 0; j < 4; j++) {
          const int q  = q0 + m*16 + lg*4 + j;
          const int kv = kv0 + n*16 + lr;
          float v = s[m][n][j] * scale;
          s[m][n][j] = (kv <= q) ? v : -1.0e9f;
        }
    // wave-parallel online softmax (butterfly over low-4 lane bits = kv dim)
    #pragma unroll
    for (int m = 0; m < 2; m++)
      #pragma unroll
      for (int j = 0; j < 4; j++) {
        float rm = fmaxf(fmaxf(s[m][0][j], s[m][1][j]), fmaxf(s[m][2][j], s[m][3][j]));
        rm = fmaxf(rm, __shfl_xor(rm, 1));
        rm = fmaxf(rm, __shfl_xor(rm, 2));
        rm = fmaxf(rm, __shfl_xor(rm, 4));
        rm = fmaxf(rm, __shfl_xor(rm, 8));
        const float mnew = fmaxf(mrow[m][j], rm);
        const float corr = __expf(mrow[m][j] - mnew);
        mrow[m][j] = mnew;
        float rs = 0.0f;
        #pragma unroll
        for (int n = 0; n < 4; n++) {
          float p = __expf(s[m][n][j] - mnew);
          s[m][n][j] = p;
          rs += p;
        }
        rs += __shfl_xor(rs, 1);
        rs += __shfl_xor(rs, 2);
        rs += __shfl_xor(rs, 4);
        rs += __shfl_xor(rs, 8);
        lsum[m][j] = lsum[m][j]*corr + rs;
        #pragma unroll
        for (int n2 = 0; n2 < 8; n2++) o[m][n2][j] *= corr;
      }
    // write P to per-wave LDS, XOR-swizzled (G4: 128B-stride rows -> bank conflict)
    #pragma unroll
    for (int m = 0; m < 2; m++)
      #pragma unroll
      for (int n = 0; n < 4; n++)
        #pragma unroll
        for (int j = 0; j < 4; j++) {
          const int prow = m*16 + lg*4 + j;
          int off = (prow*64 + n*16 + lr)*2;
          off ^= (prow & 7) << 4;
          *(bf16_t*)(Pb + off) = (__bf16)s[m][n][j];
        }
    // PV: A=P from LDS (swizzled read), B=V from Vt (contiguous 16B)
    #pragma unroll
    for (int ks = 0; ks < 2; ks++) {
      bf16x8 pa[2];
      #pragma unroll
      for (int m = 0; m < 2; m++) {
        const int prow = m*16 + lr;
        int off = prow*128 + (ks*32 + lk)*2;
        off ^= (prow & 7) << 4;
        pa[m] = *(const bf16x8*)(Pb + off);
      }
      #pragma unroll
      for (int n2 = 0; n2 < 8; n2++) {
        bf16x8 bv = *(const bf16x8*)&Vt[(size_t)((b*H_ + h)*D_ + n2*16 + lr)*L_ + kv0 + ks*32 + lk];
        o[0][n2] = __builtin_amdgcn_mfma_f32_16x16x32_bf16(pa[0], bv, o[0][n2], 0, 0, 0);
        o[1][n2] = __builtin_amdgcn_mfma_f32_16x16x32_bf16(pa[1], bv, o[1][n2], 0, 0, 0);
      }
    }
  }
  // epilogue: normalize and store bf16 O [B][L][H*D]
  #pragma unroll
  for (int m = 0; m < 2; m++)
    #pragma unroll
    for (int j = 0; j < 4; j++) {
      const float inv = 1.0f / lsum[m][j];
      const int q = q0 + m*16 + lg*4 + j;
      #pragma unroll
      for (int n2 = 0; n2 < 8; n2++)
        O[(size_t)(b*L_ + q)*F_ + h*D_ + n2*16 + lr] = (__bf16)(o[m][n2][j]*inv);
    }
}

extern "C" void kernel_launch(void* const* d_in, const int* in_sizes, int n_in,
                              void* d_out, int out_size, void* d_ws, size_t ws_size,
                              hipStream_t stream) {
  const float* x  = (const float*)d_in[0];
  const float* Wq = (const float*)d_in[1];
  const float* Wk = (const float*)d_in[2];
  const float* Wv = (const float*)d_in[3];
  const float* Wo = (const float*)d_in[4];
  const float* bo = (const float*)d_in[5];
  float* out = (float*)d_out;

  char* ws = (char*)d_ws;
  size_t off = 0;
  auto alloc = [&](size_t bytes) {
    char* p = ws + off;
    off = (off + bytes + 255) & ~(size_t)255;
    return p;
  };
  bf16_t* xb  = (bf16_t*)alloc((size_t)NROW*E_*2);   // x bf16
  bf16_t* wqt = (bf16_t*)alloc((size_t)E_*F_*2);     // Wq^T bf16 [F][E]
  bf16_t* wkt = (bf16_t*)alloc((size_t)E_*F_*2);
  bf16_t* wvt = (bf16_t*)alloc((size_t)E_*F_*2);
  bf16_t* wot = (bf16_t*)alloc((size_t)F_*E_*2);     // Wo^T bf16 [E][F]
  float2* sc  = (float2*)alloc((size_t)L_*64*sizeof(float2));
  bf16_t* qb  = (bf16_t*)alloc((size_t)NROW*F_*2);   // Q bf16 (then RoPE in-place)
  bf16_t* kb  = (bf16_t*)alloc((size_t)NROW*F_*2);
  bf16_t* vb  = (bf16_t*)alloc((size_t)NROW*F_*2);   // V bf16 (dead after transpose)
  bf16_t* vt  = (bf16_t*)alloc((size_t)NROW*F_*2);   // V^T [B][H][D][L]
  bf16_t* ob  = vb;                                  // reuse V region for attn output

  // 1. conversions / transposes / rope table
  k_convert<<<dim3((NROW*E_/4 + 255)/256), 256, 0, stream>>>(x, xb, NROW*E_/4);
  k_transpose_w<<<dim3(64, 64), 256, 0, stream>>>(Wq, wqt);
  k_transpose_w<<<dim3(64, 64), 256, 0, stream>>>(Wk, wkt);
  k_transpose_w<<<dim3(64, 64), 256, 0, stream>>>(Wv, wvt);
  k_transpose_w<<<dim3(64, 64), 256, 0, stream>>>(Wo, wot);
  k_sincos<<<dim3(L_*64/256), 256, 0, stream>>>(sc);

  // 2. QKV projections (bf16 out)
  k_gemm_bt<bf16_t, false><<<dim3(F_/128, NROW/128), 256, 0, stream>>>(xb, wqt, qb, nullptr, NROW, F_, E_);
  k_gemm_bt<bf16_t, false><<<dim3(F_/128, NROW/128), 256, 0, stream>>>(xb, wkt, kb, nullptr, NROW, F_, E_);
  k_gemm_bt<bf16_t, false><<<dim3(F_/128, NROW/128), 256, 0, stream>>>(xb, wvt, vb, nullptr, NROW, F_, E_);

  // 3. RoPE on Q and K (in place), V transpose
  k_rope<<<dim3((NROW*F_/4 + 255)/256), 256, 0, stream>>>(qb, sc, NROW*F_/4);
  k_rope<<<dim3((NROW*F_/4 + 255)/256), 256, 0, stream>>>(kb, sc, NROW*F_/4);
  k_transpose_v<<<dim3(L_/32, D_/32, B_*H_), 256, 0, stream>>>(vb, vt);

  // 4. flash attention (writes ob, bf16)
  k_attn<<<dim3(L_/128, H_, B_), 256, 0, stream>>>(qb, kb, vt, ob);

  // 5. output projection + bias (fp32 out)
  k_gemm_bt<float, true><<<dim3(E_/128, NROW/128), 256, 0, stream>>>(ob, wot, out, bo, NROW, E_, F_);
}

// Round 2
// 582.806 us; speedup vs baseline: 1.1599x; 1.1599x over previous
//
#include <hip/hip_runtime.h>
#include <hip/hip_bf16.h>
#include <stdint.h>
#include <stddef.h>

// Problem constants
#define B_   2
#define L_   2048
#define E_   2048
#define H_   16
#define D_   128
#define F_   2048          // QKV_FEATURES
#define NROW (B_*L_)       // 4096

typedef __bf16 bf16_t;
typedef __bf16 bf16x4 __attribute__((ext_vector_type(4)));
typedef __bf16 bf16x8 __attribute__((ext_vector_type(8)));
typedef float  f32x4  __attribute__((ext_vector_type(4)));

// async global->LDS, 16B per lane. LDS dest = wave-uniform base + lane*16.
__device__ __forceinline__ void gload16(const void* g, void* l) {
  __builtin_amdgcn_global_load_lds(
      (const __attribute__((address_space(1))) void*)g,
      (__attribute__((address_space(3))) void*)l, 16, 0, 0);
}

// ---------------- fp32 -> bf16 elementwise ----------------
__global__ __launch_bounds__(256) void k_convert(const float* __restrict__ in,
                                                 bf16_t* __restrict__ out, int n4) {
  int i = blockIdx.x*256 + threadIdx.x;
  if (i >= n4) return;
  float4 v = ((const float4*)in)[i];
  bf16x4 t;
  t[0] = (__bf16)v.x; t[1] = (__bf16)v.y; t[2] = (__bf16)v.z; t[3] = (__bf16)v.w;
  ((bf16x4*)out)[i] = t;
}

// ------- transpose+convert: W[2048][2048] f32 -> WT[2048][2048] bf16 -------
__global__ __launch_bounds__(256) void k_transpose_w(const float* __restrict__ in,
                                                     bf16_t* __restrict__ out) {
  __shared__ float tile[32][33];
  const int ct = blockIdx.x, rt = blockIdx.y;
  const int c = threadIdx.x & 31, r0 = threadIdx.x >> 5;
  #pragma unroll
  for (int k = 0; k < 4; k++) {
    int r = r0 + k*8;
    tile[r][c] = in[(size_t)(rt*32 + r)*2048 + ct*32 + c];
  }
  __syncthreads();
  #pragma unroll
  for (int k = 0; k < 4; k++) {
    int r = r0 + k*8;
    out[(size_t)(ct*32 + r)*2048 + rt*32 + c] = (__bf16)tile[c][r];
  }
}

// ---------------- RoPE cos/sin table: [L][64] of float2(cos,sin) ----------------
__global__ __launch_bounds__(256) void k_sincos(float2* __restrict__ sc) {
  int id = blockIdx.x*256 + threadIdx.x;   // L_*64 threads
  int t = id >> 6, i = id & 63;
  float freq = powf(10000.0f, -(float)i / 64.0f);   // theta^(-2i/D)
  float a = (float)t * freq;
  sc[id] = make_float2(cosf(a), sinf(a));
}

// ---------------- in-place RoPE on bf16 [NROW][F_] ----------------
__global__ __launch_bounds__(256) void k_rope(bf16_t* __restrict__ qk,
                                              const float2* __restrict__ sc, int n4) {
  int i = blockIdx.x*256 + threadIdx.x;    // NROW*F_/4 groups (2 pairs each)
  if (i >= n4) return;
  int e  = i << 2;
  int d  = e & (F_-1);
  int ii = (d & (D_-1)) >> 1;              // pair index within head (even)
  int t  = (e >> 11) & (L_-1);             // token position
  bf16x4 v = ((const bf16x4*)qk)[i];
  float2 cs0 = sc[t*64 + ii];
  float2 cs1 = sc[t*64 + ii + 1];
  float x0 = (float)v[0], x1 = (float)v[1], x2 = (float)v[2], x3 = (float)v[3];
  bf16x4 o;
  o[0] = (__bf16)(x0*cs0.x - x1*cs0.y);
  o[1] = (__bf16)(x0*cs0.y + x1*cs0.x);
  o[2] = (__bf16)(x2*cs1.x - x3*cs1.y);
  o[3] = (__bf16)(x2*cs1.y + x3*cs1.x);
  ((bf16x4*)qk)[i] = o;
}

// -------- transpose V: [B][L][H][D] bf16 -> Vt [B][H][D][L] bf16 --------
__global__ __launch_bounds__(256) void k_transpose_v(const bf16_t* __restrict__ in,
                                                     bf16_t* __restrict__ out) {
  __shared__ bf16_t tile[32][33];
  const int lt = blockIdx.x, dt = blockIdx.y, bh = blockIdx.z;
  const int b = bh >> 4;                   // H_=16
  const int h = bh & 15;
  const int c = threadIdx.x & 31, r0 = threadIdx.x >> 5;
  #pragma unroll
  for (int k = 0; k < 4; k++) {
    int r = r0 + k*8;
    tile[r][c] = in[(size_t)(b*L_ + lt*32 + r)*F_ + h*D_ + dt*32 + c];
  }
  __syncthreads();
  #pragma unroll
  for (int k = 0; k < 4; k++) {
    int r = r0 + k*8;
    out[(size_t)(bh*D_ + dt*32 + r)*L_ + lt*32 + c] = tile[c][r];
  }
}

// -------- GEMM: C[M][N] = A[M][K] (bf16) x BT[N][K] (bf16), fp32 accum --------
// m97 structure: 128x128 tile, BK=32, global_load_lds(16B) staging, 2 barriers/K-step.
// LDS layout is linear in tid: byte offset 16*tid (first 64 rows), 4096+16*tid (rows 64..127).
template<typename OutT, bool BIAS>
__global__ __launch_bounds__(256) void k_gemm_bt(const bf16_t* __restrict__ A,
                                                 const bf16_t* __restrict__ BT,
                                                 OutT* __restrict__ C,
                                                 const float* __restrict__ bias,
                                                 int M, int N, int K) {
  __shared__ bf16_t As[128*32];
  __shared__ bf16_t Bs[128*32];
  const int tid  = threadIdx.x;
  const int lane = tid & 63, wave = tid >> 6;
  const int wr = wave >> 1, wc = wave & 1;
  const int row0 = blockIdx.y*128, col0 = blockIdx.x*128;
  const int sr  = tid >> 2;                // staging row 0..63
  const int sc8 = (tid & 3) * 8;           // staging col 0/8/16/24
  const bf16_t* Ag = A  + (size_t)(row0 + sr)*K + sc8;
  const bf16_t* Bg = BT + (size_t)(col0 + sr)*K + sc8;
  char* AsB = (char*)As; char* BsB = (char*)Bs;
  const int lr = lane & 15, lk = (lane >> 4) * 8;
  f32x4 acc[4][4] = {};
  for (int kt = 0; kt < K; kt += 32) {
    gload16(Ag + kt,                 AsB + wave*1024);
    gload16(Ag + (size_t)64*K + kt,  AsB + 4096 + wave*1024);
    gload16(Bg + kt,                 BsB + wave*1024);
    gload16(Bg + (size_t)64*K + kt,  BsB + 4096 + wave*1024);
    __syncthreads();
    bf16x8 af[4], bb[4];
    #pragma unroll
    for (int m = 0; m < 4; m++) af[m] = *(const bf16x8*)&As[(wr*64 + m*16 + lr)*32 + lk];
    #pragma unroll
    for (int n = 0; n < 4; n++) bb[n] = *(const bf16x8*)&Bs[(wc*64 + n*16 + lr)*32 + lk];
    #pragma unroll
    for (int m = 0; m < 4; m++)
      #pragma unroll
      for (int n = 0; n < 4; n++)
        acc[m][n] = __builtin_amdgcn_mfma_f32_16x16x32_bf16(af[m], bb[n], acc[m][n], 0, 0, 0);
    __syncthreads();
  }
  // epilogue: C/D layout col=lane&15, row=(lane>>4)*4+j (m89-verified)
  #pragma unroll
  for (int m = 0; m < 4; m++) {
    #pragma unroll
    for (int n = 0; n < 4; n++) {
      const int col = col0 + wc*64 + n*16 + lr;
      const float bv = BIAS ? bias[col] : 0.0f;
      #pragma unroll
      for (int j = 0; j < 4; j++) {
        const int row = row0 + wr*64 + m*16 + (lane >> 4)*4 + j;
        C[(size_t)row*N + col] = (OutT)(acc[m][n][j] + bv);
      }
    }
  }
}

// -------- Flash attention, causal, swapped-operand MFMA form --------
// Q,K: [B][L][H*D] bf16 (RoPE'd); Vt: [B][H][D][L] bf16.
// 4 waves/block, wave owns 32 q-rows; KVBLK=64; K/V^T tiles LDS-staged
// (double-buffered, global_load_lds w/ pre-swizzled source), 1 barrier/tile.
// QK^T computed as S^T = K*Q^T so each lane owns one q-row (softmax is
// 2 shfl_xor + lane-scalar stats); PV computed as O^T = V^T * P^T.
__global__ __launch_bounds__(256) void k_attn(const bf16_t* __restrict__ Q,
                                              const bf16_t* __restrict__ K,
                                              const bf16_t* __restrict__ Vt,
                                              bf16_t* __restrict__ O) {
  __shared__ bf16_t Ks[2][64*128];    // [kv][d], 16B-chunk-swizzled by (kv&7)
  __shared__ bf16_t Vs[2][128*64];    // [d][kv], 16B-chunk-swizzled by (d&7)
  __shared__ bf16_t Pl[4][32*64];     // per-wave P^T as [q][kv], swizzled by (q&7)
  const int tid = threadIdx.x, lane = tid & 63, wave = tid >> 6;
  const int qt = (int)gridDim.x - 1 - (int)blockIdx.x;   // heavy tiles first
  const int h = blockIdx.y, b = blockIdx.z;
  const int q0 = qt*128 + wave*32;
  const int lr = lane & 15, lg = lane >> 4;
  const int swz = (lr & 7) << 4;
  char* Pb = (char*)&Pl[wave][0];

  // Q fragments in registers: aq[m2][kd] = Q[q0+m2*16+lr][kd*32+lg*8 ..+8]
  bf16x8 aq[2][4];
  #pragma unroll
  for (int m2 = 0; m2 < 2; m2++)
    #pragma unroll
    for (int kd = 0; kd < 4; kd++)
      aq[m2][kd] = *(const bf16x8*)&Q[(size_t)(b*L_ + q0 + m2*16 + lr)*F_ + h*D_ + kd*32 + lg*8];

  // staging source pointers (pre-swizzled global chunk so LDS stays linear)
  const bf16_t* Kg0 = K  + (size_t)(b*L_ + (tid >> 4))*F_ + h*D_
                        + (((tid & 15) ^ ((tid >> 4) & 7)) << 3);
  const bf16_t* Vg0 = Vt + (size_t)((b*H_ + h)*D_ + (tid >> 3))*L_
                        + (((tid & 7) ^ ((tid >> 3) & 7)) << 3);

  f32x4 o[2][8] = {};
  float mrow[2] = {-3.0e38f, -3.0e38f};
  float lsum[2] = {0.0f, 0.0f};
  const float scale2 = 0.08838834764831845f * 1.44269504088896f;  // /sqrt(D) * log2(e)
  const int ntb = 2*qt + 2;            // block covers kv < (qt+1)*128

  // prologue: stage tile 0
  {
    char* kb = (char*)&Ks[0][0] + wave*1024;
    char* vb = (char*)&Vs[0][0] + wave*1024;
    #pragma unroll
    for (int c = 0; c < 4; c++) {
      gload16(Kg0 + (size_t)(c*16)*F_, kb + c*4096);
      gload16(Vg0 + (size_t)(c*32)*L_, vb + c*4096);
    }
  }
  __syncthreads();

  int buf = 0;
  for (int t = 0; t < ntb; t++) {
    const int kv0 = t*64;
    // issue next tile's async stage before computing current (2-phase overlap)
    if (t + 1 < ntb) {
      const int kn = (t+1)*64;
      char* kb = (char*)&Ks[buf^1][0] + wave*1024;
      char* vb = (char*)&Vs[buf^1][0] + wave*1024;
      const bf16_t* kg = Kg0 + (size_t)kn*F_;
      const bf16_t* vg = Vg0 + kn;
      #pragma unroll
      for (int c = 0; c < 4; c++) {
        gload16(kg + (size_t)(c*16)*F_, kb + c*4096);
        gload16(vg + (size_t)(c*32)*L_, vb + c*4096);
      }
    }
    if (kv0 <= q0 + 31) {              // wave-uniform: skip fully-future tiles
      const char* Kb = (const char*)&Ks[buf][0];
      const char* Vb = (const char*)&Vs[buf][0];
      // ---- S^T = K * Q^T ----
      f32x4 s[2][4] = {};
      #pragma unroll
      for (int kd = 0; kd < 4; kd++) {
        bf16x8 ak[4];
        #pragma unroll
        for (int n = 0; n < 4; n++)
          ak[n] = *(const bf16x8*)(Kb + ((((n*16 + lr)*256) + kd*64 + lg*16) ^ swz));
        #pragma unroll
        for (int n = 0; n < 4; n++) {
          s[0][n] = __builtin_amdgcn_mfma_f32_16x16x32_bf16(ak[n], aq[0][kd], s[0][n], 0, 0, 0);
          s[1][n] = __builtin_amdgcn_mfma_f32_16x16x32_bf16(ak[n], aq[1][kd], s[1][n], 0, 0, 0);
        }
      }
      // ---- scale + causal mask (lane lr owns q = q0+m2*16+lr) ----
      const bool needmask = (kv0 + 63 > q0);
      #pragma unroll
      for (int m2 = 0; m2 < 2; m2++) {
        const int q = q0 + m2*16 + lr;
        #pragma unroll
        for (int n = 0; n < 4; n++)
          #pragma unroll
          for (int j = 0; j < 4; j++) {
            float v = s[m2][n][j] * scale2;
            if (needmask && (kv0 + n*16 + lg*4 + j > q)) v = -1.0e9f;
            s[m2][n][j] = v;
          }
      }
      // ---- online softmax in log2 domain: 2 shfl per row-block ----
      #pragma unroll
      for (int m2 = 0; m2 < 2; m2++) {
        float a0 = fmaxf(fmaxf(s[m2][0][0], s[m2][0][1]), fmaxf(s[m2][0][2], s[m2][0][3]));
        float a1 = fmaxf(fmaxf(s[m2][1][0], s[m2][1][1]), fmaxf(s[m2][1][2], s[m2][1][3]));
        float a2 = fmaxf(fmaxf(s[m2][2][0], s[m2][2][1]), fmaxf(s[m2][2][2], s[m2][2][3]));
        float a3 = fmaxf(fmaxf(s[m2][3][0], s[m2][3][1]), fmaxf(s[m2][3][2], s[m2][3][3]));
        float pmax = fmaxf(fmaxf(a0, a1), fmaxf(a2, a3));
        pmax = fmaxf(pmax, __shfl_xor(pmax, 16));
        pmax = fmaxf(pmax, __shfl_xor(pmax, 32));
        const float mnew = fmaxf(mrow[m2], pmax);
        const float corr = exp2f(mrow[m2] - mnew);
        mrow[m2] = mnew;
        float rs = 0.0f;
        #pragma unroll
        for (int n = 0; n < 4; n++)
          #pragma unroll
          for (int j = 0; j < 4; j++) {
            float p = exp2f(s[m2][n][j] - mnew);
            s[m2][n][j] = p;
            rs += p;
          }
        rs += __shfl_xor(rs, 16);
        rs += __shfl_xor(rs, 32);
        lsum[m2] = lsum[m2]*corr + rs;
        #pragma unroll
        for (int n2 = 0; n2 < 8; n2++) o[m2][n2] *= corr;
      }
      // ---- write P^T to per-wave LDS as [q][kv], packed 8B writes ----
      #pragma unroll
      for (int m2 = 0; m2 < 2; m2++)
        #pragma unroll
        for (int n = 0; n < 4; n++) {
          bf16x4 pw;
          pw[0] = (__bf16)s[m2][n][0]; pw[1] = (__bf16)s[m2][n][1];
          pw[2] = (__bf16)s[m2][n][2]; pw[3] = (__bf16)s[m2][n][3];
          int off = (((m2*16 + lr)*128) + n*32 + lg*8) ^ swz;
          *(bf16x4*)(Pb + off) = pw;
        }
      // ---- O^T += V^T * P^T ----
      #pragma unroll
      for (int ks = 0; ks < 2; ks++) {
        bf16x8 pb0 = *(const bf16x8*)(Pb + (((lr*128)      + ks*64 + lg*16) ^ swz));
        bf16x8 pb1 = *(const bf16x8*)(Pb + ((((16+lr)*128) + ks*64 + lg*16) ^ swz));
        #pragma unroll
        for (int n2 = 0; n2 < 8; n2++) {
          bf16x8 av = *(const bf16x8*)(Vb + ((((n2*16 + lr)*128) + ks*64 + lg*16) ^ swz));
          o[0][n2] = __builtin_amdgcn_mfma_f32_16x16x32_bf16(av, pb0, o[0][n2], 0, 0, 0);
          o[1][n2] = __builtin_amdgcn_mfma_f32_16x16x32_bf16(av, pb1, o[1][n2], 0, 0, 0);
        }
      }
    }
    __syncthreads();                   // drains stage of buf^1; all waves done with buf
    buf ^= 1;
  }
  // ---- epilogue: lane owns q = q0+m2*16+lr, d = n2*16+lg*4+j (packed 8B stores) ----
  #pragma unroll
  for (int m2 = 0; m2 < 2; m2++) {
    const float inv = 1.0f / lsum[m2];
    const int q = q0 + m2*16 + lr;
    bf16_t* orow = O + (size_t)(b*L_ + q)*F_ + h*D_ + lg*4;
    #pragma unroll
    for (int n2 = 0; n2 < 8; n2++) {
      bf16x4 ov;
      ov[0] = (__bf16)(o[m2][n2][0]*inv); ov[1] = (__bf16)(o[m2][n2][1]*inv);
      ov[2] = (__bf16)(o[m2][n2][2]*inv); ov[3] = (__bf16)(o[m2][n2][3]*inv);
      *(bf16x4*)(orow + n2*16) = ov;
    }
  }
}

extern "C" void kernel_launch(void* const* d_in, const int* in_sizes, int n_in,
                              void* d_out, int out_size, void* d_ws, size_t ws_size,
                              hipStream_t stream) {
  const float* x  = (const float*)d_in[0];
  const float* Wq = (const float*)d_in[1];
  const float* Wk = (const float*)d_in[2];
  const float* Wv = (const float*)d_in[3];
  const float* Wo = (const float*)d_in[4];
  const float* bo = (const float*)d_in[5];
  float* out = (float*)d_out;

  char* ws = (char*)d_ws;
  size_t off = 0;
  auto alloc = [&](size_t bytes) {
    char* p = ws + off;
    off = (off + bytes + 255) & ~(size_t)255;
    return p;
  };
  bf16_t* xb  = (bf16_t*)alloc((size_t)NROW*E_*2);   // x bf16
  bf16_t* wqt = (bf16_t*)alloc((size_t)E_*F_*2);     // Wq^T bf16 [F][E]
  bf16_t* wkt = (bf16_t*)alloc((size_t)E_*F_*2);
  bf16_t* wvt = (bf16_t*)alloc((size_t)E_*F_*2);
  bf16_t* wot = (bf16_t*)alloc((size_t)F_*E_*2);     // Wo^T bf16 [E][F]
  float2* sc  = (float2*)alloc((size_t)L_*64*sizeof(float2));
  bf16_t* qb  = (bf16_t*)alloc((size_t)NROW*F_*2);   // Q bf16 (then RoPE in-place)
  bf16_t* kb  = (bf16_t*)alloc((size_t)NROW*F_*2);
  bf16_t* vb  = (bf16_t*)alloc((size_t)NROW*F_*2);   // V bf16 (dead after transpose)
  bf16_t* vt  = (bf16_t*)alloc((size_t)NROW*F_*2);   // V^T [B][H][D][L]
  bf16_t* ob  = vb;                                  // reuse V region for attn output

  // 1. conversions / transposes / rope table
  k_convert<<<dim3((NROW*E_/4 + 255)/256), 256, 0, stream>>>(x, xb, NROW*E_/4);
  k_transpose_w<<<dim3(64, 64), 256, 0, stream>>>(Wq, wqt);
  k_transpose_w<<<dim3(64, 64), 256, 0, stream>>>(Wk, wkt);
  k_transpose_w<<<dim3(64, 64), 256, 0, stream>>>(Wv, wvt);
  k_transpose_w<<<dim3(64, 64), 256, 0, stream>>>(Wo, wot);
  k_sincos<<<dim3(L_*64/256), 256, 0, stream>>>(sc);

  // 2. QKV projections (bf16 out)
  k_gemm_bt<bf16_t, false><<<dim3(F_/128, NROW/128), 256, 0, stream>>>(xb, wqt, qb, nullptr, NROW, F_, E_);
  k_gemm_bt<bf16_t, false><<<dim3(F_/128, NROW/128), 256, 0, stream>>>(xb, wkt, kb, nullptr, NROW, F_, E_);
  k_gemm_bt<bf16_t, false><<<dim3(F_/128, NROW/128), 256, 0, stream>>>(xb, wvt, vb, nullptr, NROW, F_, E_);

  // 3. RoPE on Q and K (in place), V transpose
  k_rope<<<dim3((NROW*F_/4 + 255)/256), 256, 0, stream>>>(qb, sc, NROW*F_/4);
  k_rope<<<dim3((NROW*F_/4 + 255)/256), 256, 0, stream>>>(kb, sc, NROW*F_/4);
  k_transpose_v<<<dim3(L_/32, D_/32, B_*H_), 256, 0, stream>>>(vb, vt);

  // 4. flash attention (writes ob, bf16)
  k_attn<<<dim3(L_/128, H_, B_), 256, 0, stream>>>(qb, kb, vt, ob);

  // 5. output projection + bias (fp32 out)
  k_gemm_bt<float, true><<<dim3(E_/128, NROW/128), 256, 0, stream>>>(ob, wot, out, bo, NROW, E_, F_);
}

// Round 3
// 438.805 us; speedup vs baseline: 1.5405x; 1.3282x over previous
//
#include <hip/hip_runtime.h>
#include <hip/hip_bf16.h>
#include <stdint.h>
#include <stddef.h>

// Problem constants
#define B_   2
#define L_   2048
#define E_   2048
#define H_   16
#define D_   128
#define F_   2048          // QKV_FEATURES
#define NROW (B_*L_)       // 4096
#define QS   6144          // fused qkv row stride (3*F_)

typedef __bf16 bf16_t;
typedef __bf16 bf16x4 __attribute__((ext_vector_type(4)));
typedef __bf16 bf16x8 __attribute__((ext_vector_type(8)));
typedef float  f32x4  __attribute__((ext_vector_type(4)));

// async global->LDS, 16B per lane. LDS dest = wave-uniform base + lane*16.
__device__ __forceinline__ void gload16(const void* g, void* l) {
  __builtin_amdgcn_global_load_lds(
      (const __attribute__((address_space(1))) void*)g,
      (__attribute__((address_space(3))) void*)l, 16, 0, 0);
}

// ---------------- fp32 -> bf16 elementwise ----------------
__global__ __launch_bounds__(256) void k_convert(const float* __restrict__ in,
                                                 bf16_t* __restrict__ out, int n4) {
  int i = blockIdx.x*256 + threadIdx.x;
  if (i >= n4) return;
  float4 v = ((const float4*)in)[i];
  bf16x4 t;
  t[0] = (__bf16)v.x; t[1] = (__bf16)v.y; t[2] = (__bf16)v.z; t[3] = (__bf16)v.w;
  ((bf16x4*)out)[i] = t;
}

// ------- transpose+convert: W[2048][2048] f32 -> WT[2048][2048] bf16 -------
__global__ __launch_bounds__(256) void k_transpose_w(const float* __restrict__ in,
                                                     bf16_t* __restrict__ out) {
  __shared__ float tile[32][33];
  const int ct = blockIdx.x, rt = blockIdx.y;
  const int c = threadIdx.x & 31, r0 = threadIdx.x >> 5;
  #pragma unroll
  for (int k = 0; k < 4; k++) {
    int r = r0 + k*8;
    tile[r][c] = in[(size_t)(rt*32 + r)*2048 + ct*32 + c];
  }
  __syncthreads();
  #pragma unroll
  for (int k = 0; k < 4; k++) {
    int r = r0 + k*8;
    out[(size_t)(ct*32 + r)*2048 + rt*32 + c] = (__bf16)tile[c][r];
  }
}

// ---------------- RoPE cos/sin table: [L][64] of float2(cos,sin) ----------------
__global__ __launch_bounds__(256) void k_sincos(float2* __restrict__ sc) {
  int id = blockIdx.x*256 + threadIdx.x;   // L_*64 threads
  int t = id >> 6, i = id & 63;
  float freq = powf(10000.0f, -(float)i / 64.0f);   // theta^(-2i/D)
  float a = (float)t * freq;
  sc[id] = make_float2(cosf(a), sinf(a));
}

// ---------------- in-place RoPE on bf16 slice of qkv [NROW][QS] ----------------
// scale is folded into cos/sin in f32 (no extra bf16 rounding error).
__global__ __launch_bounds__(256) void k_rope(bf16_t* __restrict__ qk,
                                              const float2* __restrict__ sc,
                                              float scale, int n4) {
  int i = blockIdx.x*256 + threadIdx.x;    // NROW*F_/4 groups (2 pairs each)
  if (i >= n4) return;
  int e  = i << 2;
  int d  = e & (F_-1);
  int ii = (d & (D_-1)) >> 1;              // pair index within head (even)
  int r  = e >> 11;                        // row (token) index
  int t  = r & (L_-1);                     // token position
  bf16_t* p = qk + (size_t)r*QS + d;
  bf16x4 v = *(const bf16x4*)p;
  float2 cs0 = sc[t*64 + ii];
  float2 cs1 = sc[t*64 + ii + 1];
  cs0.x *= scale; cs0.y *= scale; cs1.x *= scale; cs1.y *= scale;
  float x0 = (float)v[0], x1 = (float)v[1], x2 = (float)v[2], x3 = (float)v[3];
  bf16x4 o;
  o[0] = (__bf16)(x0*cs0.x - x1*cs0.y);
  o[1] = (__bf16)(x0*cs0.y + x1*cs0.x);
  o[2] = (__bf16)(x2*cs1.x - x3*cs1.y);
  o[3] = (__bf16)(x2*cs1.y + x3*cs1.x);
  *(bf16x4*)p = o;
}

// -------- transpose V: qkv v-slice [B*L][QS] bf16 -> Vt [B][H][D][L] bf16 --------
__global__ __launch_bounds__(256) void k_transpose_v(const bf16_t* __restrict__ in,
                                                     bf16_t* __restrict__ out) {
  __shared__ bf16_t tile[32][33];
  const int lt = blockIdx.x, dt = blockIdx.y, bh = blockIdx.z;
  const int b = bh >> 4;                   // H_=16
  const int h = bh & 15;
  const int c = threadIdx.x & 31, r0 = threadIdx.x >> 5;
  #pragma unroll
  for (int k = 0; k < 4; k++) {
    int r = r0 + k*8;
    tile[r][c] = in[(size_t)(b*L_ + lt*32 + r)*QS + h*D_ + dt*32 + c];
  }
  __syncthreads();
  #pragma unroll
  for (int k = 0; k < 4; k++) {
    int r = r0 + k*8;
    out[(size_t)(bh*D_ + dt*32 + r)*L_ + lt*32 + c] = tile[c][r];
  }
}

// -------- GEMM: C[M][N] = A[M][K] (bf16) x BT[N][K] (bf16), fp32 accum --------
// 128x128 tile, BK=64, global_load_lds(16B) staging with T2 XOR-swizzle
// (pre-swizzled global source, linear LDS dest), 2 barriers per 64-K-step.
// 1D grid with XCD-aware block swizzle (requires nwg % 8 == 0).
template<typename OutT, bool BIAS>
__global__ __launch_bounds__(256) void k_gemm_bt(const bf16_t* __restrict__ A,
                                                 const bf16_t* __restrict__ BT,
                                                 OutT* __restrict__ C,
                                                 const float* __restrict__ bias,
                                                 int M, int N, int K) {
  __shared__ bf16_t As[128*64];   // [128 rows][64 cols], 16B chunks XOR-swizzled by row&7
  __shared__ bf16_t Bs[128*64];
  const int tid  = threadIdx.x;
  const int lane = tid & 63, wave = tid >> 6;
  const int wr = wave >> 1, wc = wave & 1;
  const int nbx = N >> 7, nwg = nbx * (M >> 7);
  int bid = blockIdx.x;
  const int cpx = nwg >> 3;
  bid = (bid & 7)*cpx + (bid >> 3);        // XCD swizzle (bijective: nwg%8==0)
  const int bx = bid % nbx, by = bid / nbx;
  const int row0 = by*128, col0 = bx*128;
  // staging: per matrix, 4 instrs of 4KB. instr i: rows i*32+(tid>>3), chunk tid&7.
  const int sr  = tid >> 3;                // 0..31
  const int sxe = ((tid & 7) ^ (sr & 7)) << 3;  // pre-swizzled source elem offset
  const bf16_t* Ag = A  + (size_t)(row0 + sr)*K + sxe;
  const bf16_t* Bg = BT + (size_t)(col0 + sr)*K + sxe;
  char* AsB = (char*)As; char* BsB = (char*)Bs;
  const int lr = lane & 15, lg = lane >> 4;
  f32x4 acc[4][4] = {};
  for (int kt = 0; kt < K; kt += 64) {
    #pragma unroll
    for (int i = 0; i < 4; i++) {
      gload16(Ag + (size_t)i*32*K + kt, AsB + i*4096 + wave*1024);
      gload16(Bg + (size_t)i*32*K + kt, BsB + i*4096 + wave*1024);
    }
    __syncthreads();
    #pragma unroll
    for (int kd = 0; kd < 2; kd++) {
      bf16x8 af[4], bb[4];
      #pragma unroll
      for (int m = 0; m < 4; m++) {
        const int row = wr*64 + m*16 + lr;
        af[m] = *(const bf16x8*)(AsB + row*128 + (((kd*4 + lg) ^ (lr & 7)) << 4));
      }
      #pragma unroll
      for (int n = 0; n < 4; n++) {
        const int row = wc*64 + n*16 + lr;
        bb[n] = *(const bf16x8*)(BsB + row*128 + (((kd*4 + lg) ^ (lr & 7)) << 4));
      }
      __builtin_amdgcn_s_setprio(1);
      #pragma unroll
      for (int m = 0; m < 4; m++)
        #pragma unroll
        for (int n = 0; n < 4; n++)
          acc[m][n] = __builtin_amdgcn_mfma_f32_16x16x32_bf16(af[m], bb[n], acc[m][n], 0, 0, 0);
      __builtin_amdgcn_s_setprio(0);
    }
    __syncthreads();
  }
  // epilogue: C/D layout col=lane&15, row=(lane>>4)*4+j (m89-verified)
  #pragma unroll
  for (int m = 0; m < 4; m++) {
    #pragma unroll
    for (int n = 0; n < 4; n++) {
      const int col = col0 + wc*64 + n*16 + lr;
      const float bv = BIAS ? bias[col] : 0.0f;
      #pragma unroll
      for (int j = 0; j < 4; j++) {
        const int row = row0 + wr*64 + m*16 + lg*4 + j;
        C[(size_t)row*N + col] = (OutT)(acc[m][n][j] + bv);
      }
    }
  }
}

// -------- Flash attention tile compute (swapped-operand form) --------
// Lane (lr,lg): q-row = wq0+lr; S^T[kv=n*16+lg*4+j][q=lr]. Scores arrive
// pre-scaled by 1/sqrt(D)*log2e (folded into Q's RoPE) -> exp2f softmax.
template<bool MASK>
__device__ __forceinline__ void attn_tile(
    int kv0, int wq0, int lr, int lg,
    const char* __restrict__ Kb, const char* __restrict__ Vb, char* __restrict__ Pb,
    const bf16x8 (&aq)[4], f32x4 (&o)[8], float& mrow, float& lsum) {
  const int swz = (lr & 7) << 4;
  // ---- S^T = K * Q^T ----
  f32x4 s[4] = {};
  #pragma unroll
  for (int kd = 0; kd < 4; kd++) {
    bf16x8 ak[4];
    #pragma unroll
    for (int n = 0; n < 4; n++)
      ak[n] = *(const bf16x8*)(Kb + (n*16 + lr)*256 + (((kd*4 + lg) << 4) ^ swz));
    __builtin_amdgcn_s_setprio(1);
    #pragma unroll
    for (int n = 0; n < 4; n++)
      s[n] = __builtin_amdgcn_mfma_f32_16x16x32_bf16(ak[n], aq[kd], s[n], 0, 0, 0);
    __builtin_amdgcn_s_setprio(0);
  }
  if (MASK) {
    const int q = wq0 + lr;
    #pragma unroll
    for (int n = 0; n < 4; n++)
      #pragma unroll
      for (int j = 0; j < 4; j++)
        if (kv0 + n*16 + lg*4 + j > q) s[n][j] = -30000.0f;   // log2-domain -inf
  }
  // ---- online softmax: row-max over 16 local + 2 shfl (lg groups) ----
  float pmax = fmaxf(
      fmaxf(fmaxf(fmaxf(s[0][0], s[0][1]), fmaxf(s[0][2], s[0][3])),
            fmaxf(fmaxf(s[1][0], s[1][1]), fmaxf(s[1][2], s[1][3]))),
      fmaxf(fmaxf(fmaxf(s[2][0], s[2][1]), fmaxf(s[2][2], s[2][3])),
            fmaxf(fmaxf(s[3][0], s[3][1]), fmaxf(s[3][2], s[3][3]))));
  pmax = fmaxf(pmax, __shfl_xor(pmax, 16));
  pmax = fmaxf(pmax, __shfl_xor(pmax, 32));
  // defer-max (T13): skip rescale while max growth <= 8 (P bounded by 2^8)
  if (!__all(pmax - mrow <= 8.0f)) {
    const float mnew = fmaxf(mrow, pmax);
    const float corr = exp2f(mrow - mnew);
    mrow = mnew;
    lsum *= corr;
    #pragma unroll
    for (int n2 = 0; n2 < 8; n2++) o[n2] *= corr;
  }
  float rs = 0.0f;
  #pragma unroll
  for (int n = 0; n < 4; n++)
    #pragma unroll
    for (int j = 0; j < 4; j++) {
      float p = exp2f(s[n][j] - mrow);
      s[n][j] = p;
      rs += p;
    }
  rs += __shfl_xor(rs, 16);
  rs += __shfl_xor(rs, 32);
  lsum += rs;
  // ---- P -> per-wave LDS [q=16][kv=64], swizzled 8B writes ----
  #pragma unroll
  for (int n = 0; n < 4; n++) {
    bf16x4 pw;
    pw[0] = (__bf16)s[n][0]; pw[1] = (__bf16)s[n][1];
    pw[2] = (__bf16)s[n][2]; pw[3] = (__bf16)s[n][3];
    *(bf16x4*)(Pb + ((lr*128 + n*32 + lg*8) ^ swz)) = pw;
  }
  // ---- O^T += V^T * P ----
  #pragma unroll
  for (int ks = 0; ks < 2; ks++) {
    bf16x8 pb = *(const bf16x8*)(Pb + ((lr*128 + ks*64 + lg*16) ^ swz));
    __builtin_amdgcn_s_setprio(1);
    #pragma unroll
    for (int n2 = 0; n2 < 8; n2++) {
      bf16x8 av = *(const bf16x8*)(Vb + (n2*16 + lr)*128 + (((ks*4 + lg) << 4) ^ swz));
      o[n2] = __builtin_amdgcn_mfma_f32_16x16x32_bf16(av, pb, o[n2], 0, 0, 0);
    }
    __builtin_amdgcn_s_setprio(0);
  }
}

// -------- Flash attention, causal. 8 waves x 16 q-rows = 128 q-rows/block. --------
// QKV fused buffer [B*L][QS]; Vt [B][H][D][L]; O [B*L][F_] bf16.
// K/V^T LDS-staged (dbuf, global_load_lds, pre-swizzled source); full/boundary split.
__global__ __launch_bounds__(512, 4) void k_attn(const bf16_t* __restrict__ QKV,
                                                 const bf16_t* __restrict__ Vt,
                                                 bf16_t* __restrict__ O) {
  __shared__ bf16_t Ks[2][64*128];    // 16KB each buf
  __shared__ bf16_t Vs[2][128*64];    // 16KB each buf
  __shared__ bf16_t Pl[8][16*64];     // 2KB per wave
  const int tid = threadIdx.x, lane = tid & 63, wave = tid >> 6;
  const int qt = (int)gridDim.x - 1 - (int)blockIdx.x;   // heavy tiles first
  const int h = blockIdx.y, b = blockIdx.z;
  const int wq0 = qt*128 + wave*16;
  const int lr = lane & 15, lg = lane >> 4;
  char* Pb = (char*)&Pl[wave][0];
  const bf16_t* Q = QKV;
  const bf16_t* K = QKV + F_;

  // Q frags: aq[kd] = Q[wq0+lr][h*D + kd*32 + lg*8 ..+8]  (pre-scaled by RoPE)
  bf16x8 aq[4];
  #pragma unroll
  for (int kd = 0; kd < 4; kd++)
    aq[kd] = *(const bf16x8*)&Q[(size_t)(b*L_ + wq0 + lr)*QS + h*D_ + kd*32 + lg*8];

  // staging source pointers (pre-swizzled 16B chunk, linear LDS dest)
  const int kr = tid >> 4, kc = tid & 15;     // K: row kr(+i*32), chunk kc of 16
  const bf16_t* Kg0 = K + (size_t)(b*L_ + kr)*QS + h*D_ + ((kc ^ (kr & 7)) << 3);
  const int vr = tid >> 3, vc = tid & 7;      // V: d-row vr(+i*64), chunk vc of 8
  const bf16_t* Vg0 = Vt + (size_t)((b*H_ + h)*D_ + vr)*L_ + ((vc ^ (vr & 7)) << 3);

  f32x4 o[8] = {};
  float mrow = -3.0e38f, lsum = 0.0f;
  const int ntb   = 2*qt + 2;                 // block covers kv < (qt+1)*128
  const int nfull = (wq0 + 1) >> 6;           // fully-unmasked tiles for this wave
  const int nmine = ((wq0 + 15) >> 6) + 1;    // tiles this wave computes (nfull+1)

  // prologue: stage tile 0
  {
    char* kb = (char*)&Ks[0][0] + wave*1024;
    char* vb = (char*)&Vs[0][0] + wave*1024;
    gload16(Kg0,                    kb);
    gload16(Kg0 + (size_t)32*QS,    kb + 8192);
    gload16(Vg0,                    vb);
    gload16(Vg0 + (size_t)64*L_,    vb + 8192);
  }
  __syncthreads();

  int buf = 0;
  for (int t = 0; t < ntb; t++) {
    if (t + 1 < ntb) {                         // async stage next tile
      const int kn = (t+1)*64;
      char* kb = (char*)&Ks[buf^1][0] + wave*1024;
      char* vb = (char*)&Vs[buf^1][0] + wave*1024;
      const bf16_t* kg = Kg0 + (size_t)kn*QS;
      const bf16_t* vg = Vg0 + kn;
      gload16(kg,                 kb);
      gload16(kg + (size_t)32*QS, kb + 8192);
      gload16(vg,                 vb);
      gload16(vg + (size_t)64*L_, vb + 8192);
    }
    const char* Kb = (const char*)&Ks[buf][0];
    const char* Vb = (const char*)&Vs[buf][0];
    if (t < nfull)
      attn_tile<false>(t*64, wq0, lr, lg, Kb, Vb, Pb, aq, o, mrow, lsum);
    else if (t < nmine)
      attn_tile<true >(t*64, wq0, lr, lg, Kb, Vb, Pb, aq, o, mrow, lsum);
    __syncthreads();                           // drains stage; all waves done with buf
    buf ^= 1;
  }
  // ---- epilogue: lane holds O^T[d=n2*16+lg*4+j][q=lr] ----
  const float inv = 1.0f / lsum;
  bf16_t* orow = O + (size_t)(b*L_ + wq0 + lr)*F_ + h*D_ + lg*4;
  #pragma unroll
  for (int n2 = 0; n2 < 8; n2++) {
    bf16x4 ov;
    ov[0] = (__bf16)(o[n2][0]*inv); ov[1] = (__bf16)(o[n2][1]*inv);
    ov[2] = (__bf16)(o[n2][2]*inv); ov[3] = (__bf16)(o[n2][3]*inv);
    *(bf16x4*)(orow + n2*16) = ov;
  }
}

extern "C" void kernel_launch(void* const* d_in, const int* in_sizes, int n_in,
                              void* d_out, int out_size, void* d_ws, size_t ws_size,
                              hipStream_t stream) {
  const float* x  = (const float*)d_in[0];
  const float* Wq = (const float*)d_in[1];
  const float* Wk = (const float*)d_in[2];
  const float* Wv = (const float*)d_in[3];
  const float* Wo = (const float*)d_in[4];
  const float* bo = (const float*)d_in[5];
  float* out = (float*)d_out;

  char* ws = (char*)d_ws;
  size_t off = 0;
  auto alloc = [&](size_t bytes) {
    char* p = ws + off;
    off = (off + bytes + 255) & ~(size_t)255;
    return p;
  };
  bf16_t* xb    = (bf16_t*)alloc((size_t)NROW*E_*2);     // x bf16; reused as attn out
  bf16_t* wqkvt = (bf16_t*)alloc((size_t)3*F_*E_*2);     // [Wq^T;Wk^T;Wv^T] bf16 [6144][2048]
  bf16_t* wot   = (bf16_t*)alloc((size_t)F_*E_*2);       // Wo^T bf16 [E][F]
  float2* sc    = (float2*)alloc((size_t)L_*64*sizeof(float2));
  bf16_t* qkv   = (bf16_t*)alloc((size_t)NROW*QS*2);     // fused QKV [4096][6144]
  bf16_t* vt    = (bf16_t*)alloc((size_t)NROW*F_*2);     // V^T [B][H][D][L]
  bf16_t* ob    = xb;                                    // attn output (xb dead by then)

  const float scale2 = 0.08838834764831845f * 1.44269504088896f;  // 1/sqrt(D) * log2(e)

  // 1. conversions / transposes / rope table
  k_convert<<<dim3((NROW*E_/4 + 255)/256), 256, 0, stream>>>(x, xb, NROW*E_/4);
  k_transpose_w<<<dim3(64, 64), 256, 0, stream>>>(Wq, wqkvt);
  k_transpose_w<<<dim3(64, 64), 256, 0, stream>>>(Wk, wqkvt + (size_t)F_*E_);
  k_transpose_w<<<dim3(64, 64), 256, 0, stream>>>(Wv, wqkvt + (size_t)2*F_*E_);
  k_transpose_w<<<dim3(64, 64), 256, 0, stream>>>(Wo, wot);
  k_sincos<<<dim3(L_*64/256), 256, 0, stream>>>(sc);

  // 2. fused QKV projection: [4096][2048] x [6144][2048]^T -> [4096][6144]
  k_gemm_bt<bf16_t, false><<<dim3((QS/128)*(NROW/128)), 256, 0, stream>>>(
      xb, wqkvt, qkv, nullptr, NROW, QS, E_);

  // 3. RoPE on Q (scale folded) and K slices; V transpose
  k_rope<<<dim3((NROW*F_/4 + 255)/256), 256, 0, stream>>>(qkv,      sc, scale2, NROW*F_/4);
  k_rope<<<dim3((NROW*F_/4 + 255)/256), 256, 0, stream>>>(qkv + F_, sc, 1.0f,   NROW*F_/4);
  k_transpose_v<<<dim3(L_/32, D_/32, B_*H_), 256, 0, stream>>>(qkv + 2*F_, vt);

  // 4. flash attention (writes ob = xb, bf16)
  k_attn<<<dim3(L_/128, H_, B_), 512, 0, stream>>>(qkv, vt, ob);

  // 5. output projection + bias (fp32 out)
  k_gemm_bt<float, true><<<dim3((E_/128)*(NROW/128)), 256, 0, stream>>>(
      ob, wot, out, bo, NROW, E_, F_);
}